// Round 1
// baseline (562.033 us; speedup 1.0000x reference)
//
#include <hip/hip_runtime.h>

typedef unsigned short u16;
typedef __bf16  bf16x8 __attribute__((ext_vector_type(8)));
typedef float   f32x4  __attribute__((ext_vector_type(4)));

#define B_SZ   1024
#define V_SZ   6890
#define J_SZ   52
#define NB_SZ  16
#define NPOSE  459
#define N3     20670   /* V*3 */
#define NPAD   20736   /* 162*128, padded N for GEMM */
#define KG     480     /* 459 pose + 16 betas, zero-padded to 480 */

__constant__ int PARENTS_D[52] = {-1,0,0,0,1,2,3,4,5,6,7,8,9,9,9,12,13,14,16,17,18,19,20,22,23,
                                  20,25,26,20,28,29,20,31,32,20,34,35,21,37,38,21,40,41,21,43,44,
                                  21,46,47,21,49,50};

__device__ __forceinline__ u16 f2b(float f) {
  union { float f; unsigned u; } v; v.f = f;
  unsigned r = (v.u + 0x7FFFu + ((v.u >> 16) & 1u)) >> 16;
  return (u16)r;
}
__device__ __forceinline__ float b2f(u16 h) {
  union { unsigned u; float f; } v; v.u = ((unsigned)h) << 16;
  return v.f;
}
__device__ __forceinline__ void async16(const void* g, void* l) {
  __builtin_amdgcn_global_load_lds((const __attribute__((address_space(1))) void*)g,
                                   (__attribute__((address_space(3))) void*)l, 16, 0, 0);
}

// ---------------------------------------------------------------------------
// K0: build PDt[n][k] (bf16, K-contiguous): rows k<459 = posedirs (transposed
// via LDS tile), k in [459,475) = shapedirs, rest 0. n padded to NPAD with 0.
// ---------------------------------------------------------------------------
__global__ __launch_bounds__(256) void k0_build_pdt(const float* __restrict__ posedirs,
                                                    const float* __restrict__ shapedirs,
                                                    u16* __restrict__ PDt)
{
  __shared__ u16 tile[32][33];
  const int tx = threadIdx.x;          // 32 (n within tile on load, k on store)
  const int ty = threadIdx.y;          // 8
  const int n0 = blockIdx.x * 32;
  const int k0 = blockIdx.y * 32;
#pragma unroll
  for (int i = 0; i < 4; ++i) {
    int k = k0 + ty + i*8;
    int n = n0 + tx;
    float val = 0.f;
    if (n < N3) {
      if (k < NPOSE)              val = posedirs[(size_t)k * N3 + n];
      else if (k < NPOSE + NB_SZ) val = shapedirs[(size_t)n * NB_SZ + (k - NPOSE)];
    }
    tile[ty + i*8][tx] = f2b(val);
  }
  __syncthreads();
#pragma unroll
  for (int i = 0; i < 4; ++i) {
    int n = n0 + ty + i*8;
    int k = k0 + tx;
    PDt[(size_t)n * KG + k] = tile[tx][ty + i*8];
  }
}

// ---------------------------------------------------------------------------
// K1: per batch: rot6d -> R, joints, kinematic chain -> A (3x4 fp32),
// pose_feature||betas -> PF bf16 row of length KG (zero padded).
// ---------------------------------------------------------------------------
__global__ __launch_bounds__(64) void k1_prep(const float* __restrict__ body_pose,
                                              const float* __restrict__ betas,
                                              const float* __restrict__ global_orient,
                                              const float* __restrict__ J_template,
                                              const float* __restrict__ J_shapedirs,
                                              float* __restrict__ Afp,
                                              u16* __restrict__ PF)
{
  __shared__ float R[J_SZ][9];
  __shared__ float jts[J_SZ][3];
  __shared__ float G[J_SZ][12];
  const int b   = blockIdx.x;
  const int tid = threadIdx.x;

  if (tid < J_SZ) {
    const float* d6 = (tid == 0) ? &global_orient[(size_t)b * 6]
                                 : &body_pose[((size_t)b * 51 + (tid - 1)) * 6];
    float a1x = d6[0], a1y = d6[1], a1z = d6[2];
    float a2x = d6[3], a2y = d6[4], a2z = d6[5];
    float inv1 = rsqrtf(a1x*a1x + a1y*a1y + a1z*a1z);
    float b1x = a1x*inv1, b1y = a1y*inv1, b1z = a1z*inv1;
    float d   = b1x*a2x + b1y*a2y + b1z*a2z;
    float ux = a2x - d*b1x, uy = a2y - d*b1y, uz = a2z - d*b1z;
    float inv2 = rsqrtf(ux*ux + uy*uy + uz*uz);
    float b2x = ux*inv2, b2y = uy*inv2, b2z = uz*inv2;
    float b3x = b1y*b2z - b1z*b2y;
    float b3y = b1z*b2x - b1x*b2z;
    float b3z = b1x*b2y - b1y*b2x;
    R[tid][0]=b1x; R[tid][1]=b1y; R[tid][2]=b1z;
    R[tid][3]=b2x; R[tid][4]=b2y; R[tid][5]=b2z;
    R[tid][6]=b3x; R[tid][7]=b3y; R[tid][8]=b3z;
#pragma unroll
    for (int c = 0; c < 3; ++c) {
      float s = J_template[tid*3 + c];
#pragma unroll
      for (int k = 0; k < NB_SZ; ++k)
        s += betas[(size_t)b*NB_SZ + k] * J_shapedirs[(tid*3 + c)*NB_SZ + k];
      jts[tid][c] = s;
    }
  }
  __syncthreads();

  if (tid == 0) {   // serial kinematic chain (52 x 3x4 multiplies, trivial)
#pragma unroll
    for (int c = 0; c < 3; ++c) {
      G[0][c*4+0] = R[0][c*3+0];
      G[0][c*4+1] = R[0][c*3+1];
      G[0][c*4+2] = R[0][c*3+2];
      G[0][c*4+3] = jts[0][c];
    }
    for (int j = 1; j < J_SZ; ++j) {
      int p = PARENTS_D[j];
      float r0 = jts[j][0] - jts[p][0];
      float r1 = jts[j][1] - jts[p][1];
      float r2 = jts[j][2] - jts[p][2];
      for (int c = 0; c < 3; ++c) {
        float g0 = G[p][c*4+0], g1 = G[p][c*4+1], g2 = G[p][c*4+2];
        G[j][c*4+0] = g0*R[j][0] + g1*R[j][3] + g2*R[j][6];
        G[j][c*4+1] = g0*R[j][1] + g1*R[j][4] + g2*R[j][7];
        G[j][c*4+2] = g0*R[j][2] + g1*R[j][5] + g2*R[j][8];
        G[j][c*4+3] = g0*r0 + g1*r1 + g2*r2 + G[p][c*4+3];
      }
    }
  }
  __syncthreads();

  if (tid < J_SZ) {  // t_corr + write A
    float o[12];
#pragma unroll
    for (int i = 0; i < 12; ++i) o[i] = G[tid][i];
#pragma unroll
    for (int c = 0; c < 3; ++c)
      o[c*4+3] -= o[c*4+0]*jts[tid][0] + o[c*4+1]*jts[tid][1] + o[c*4+2]*jts[tid][2];
#pragma unroll
    for (int i = 0; i < 12; ++i) Afp[((size_t)b*J_SZ + tid)*12 + i] = o[i];
  }

  for (int k = tid; k < KG; k += 64) {  // PF row: pose_feature | betas | 0-pad
    float val = 0.f;
    if (k < NPOSE) {
      int j  = k / 9 + 1;
      int rc = k - (j - 1) * 9;
      val = R[j][rc] - ((rc == 0 || rc == 4 || rc == 8) ? 1.f : 0.f);
    } else if (k < NPOSE + NB_SZ) {
      val = betas[(size_t)b*NB_SZ + (k - NPOSE)];
    }
    PF[(size_t)b*KG + k] = f2b(val);
  }
}

// ---------------------------------------------------------------------------
// K2: v_posed(B, NPAD) = PF(B,KG) @ PDt^T + v_template bias, bf16 MFMA.
// 128x128 tile, BK=32, 4 waves each 64x64. global_load_lds(16B) staging with
// XOR swizzle s(r)=(r+(r>>2))&3 on 16B chunks -> 2-way (free) LDS b128 reads.
// ---------------------------------------------------------------------------
__global__ __launch_bounds__(256) void k2_gemm(const u16* __restrict__ PF,
                                               const u16* __restrict__ PDt,
                                               const float* __restrict__ vtmpl,
                                               u16* __restrict__ VP)
{
  __shared__ __align__(16) u16 lA[128*32];
  __shared__ __align__(16) u16 lB[128*32];
  const int tid  = threadIdx.x;
  const int lane = tid & 63;
  const int w    = tid >> 6;
  const int n0   = blockIdx.x * 128;
  const int b0   = blockIdx.y * 128;
  const int moff = (w & 1) * 64;
  const int noff = (w >> 1) * 64;
  const int q    = lane >> 4;
  const int lrow = lane & 15;

  f32x4 acc[4][4];
#pragma unroll
  for (int i = 0; i < 4; ++i)
#pragma unroll
    for (int j = 0; j < 4; ++j) { f32x4 z = {0.f,0.f,0.f,0.f}; acc[i][j] = z; }

  int aoff[4], boff[4];
#pragma unroll
  for (int i = 0; i < 4; ++i) {
    int ra = moff + i*16 + lrow;
    aoff[i] = ra*32 + (q ^ ((ra + (ra >> 2)) & 3)) * 8;
    int rb = noff + i*16 + lrow;
    boff[i] = rb*32 + (q ^ ((rb + (rb >> 2)) & 3)) * 8;
  }
  int srow[2], schunk[2];
#pragma unroll
  for (int t = 0; t < 2; ++t) {
    int i = (t*4 + w)*64 + lane;     // slot in [0,512)
    int r = i >> 2;
    srow[t]   = r;
    schunk[t] = (i & 3) ^ ((r + (r >> 2)) & 3);  // logical chunk for this phys slot
  }

  for (int k0 = 0; k0 < KG; k0 += 32) {
#pragma unroll
    for (int t = 0; t < 2; ++t) {
      async16(PF  + (size_t)(b0 + srow[t])*KG + k0 + schunk[t]*8, &lA[(t*4 + w)*512]);
      async16(PDt + (size_t)(n0 + srow[t])*KG + k0 + schunk[t]*8, &lB[(t*4 + w)*512]);
    }
    __syncthreads();
    bf16x8 af[4], bfv[4];
#pragma unroll
    for (int i = 0; i < 4; ++i) af[i]  = *(const bf16x8*)&lA[aoff[i]];
#pragma unroll
    for (int i = 0; i < 4; ++i) bfv[i] = *(const bf16x8*)&lB[boff[i]];
#pragma unroll
    for (int i = 0; i < 4; ++i)
#pragma unroll
      for (int j = 0; j < 4; ++j)
        acc[i][j] = __builtin_amdgcn_mfma_f32_16x16x32_bf16(af[i], bfv[j], acc[i][j], 0, 0, 0);
    __syncthreads();
  }

  // epilogue: C/D layout col=lane&15, row=q*4+reg  (m89/m91-verified)
#pragma unroll
  for (int i = 0; i < 4; ++i) {
    int brow = b0 + moff + i*16 + q*4;
#pragma unroll
    for (int j = 0; j < 4; ++j) {
      int n = n0 + noff + j*16 + lrow;
      if (n < N3) {
        float bias = vtmpl[n];
#pragma unroll
        for (int r = 0; r < 4; ++r)
          VP[(size_t)(brow + r)*NPAD + n] = f2b(acc[i][j][r] + bias);
      }
    }
  }
}

// ---------------------------------------------------------------------------
// K3: verts[b,v,:] = (sum_j w[v,j] A[b,j]) * [v_posed,1] + transl. fp32 VALU.
// A[b] staged in LDS; A[j] register-cached across 4 verts/thread.
// ---------------------------------------------------------------------------
__global__ __launch_bounds__(256) void k3_blend(const float* __restrict__ Afp,
                                                const float* __restrict__ transl,
                                                const float* __restrict__ lbsw,
                                                const u16* __restrict__ VP,
                                                float* __restrict__ out)
{
  __shared__ float As[J_SZ*12];
  __shared__ float trs[3];
  const int tid = threadIdx.x;
  const int b   = blockIdx.y;
  for (int i = tid; i < J_SZ*12; i += 256) As[i] = Afp[(size_t)b*(J_SZ*12) + i];
  if (tid < 3) trs[tid] = transl[b*3 + tid];
  __syncthreads();

  int vv[4]; bool act[4];
#pragma unroll
  for (int u = 0; u < 4; ++u) {
    vv[u]  = blockIdx.x*1024 + u*256 + tid;
    act[u] = vv[u] < V_SZ;
  }
  f32x4 T0[4], T1[4], T2[4];
#pragma unroll
  for (int u = 0; u < 4; ++u) { f32x4 z = {0.f,0.f,0.f,0.f}; T0[u]=z; T1[u]=z; T2[u]=z; }

  for (int j4 = 0; j4 < 13; ++j4) {
    f32x4 wv[4];
#pragma unroll
    for (int u = 0; u < 4; ++u) {
      f32x4 z = {0.f,0.f,0.f,0.f};
      wv[u] = act[u] ? *(const f32x4*)&lbsw[(size_t)vv[u]*J_SZ + j4*4] : z;
    }
#pragma unroll
    for (int jj = 0; jj < 4; ++jj) {
      int j = j4*4 + jj;
      f32x4 A0 = *(const f32x4*)&As[j*12 + 0];
      f32x4 A1 = *(const f32x4*)&As[j*12 + 4];
      f32x4 A2 = *(const f32x4*)&As[j*12 + 8];
#pragma unroll
      for (int u = 0; u < 4; ++u) {
        float wj = wv[u][jj];
        T0[u] += wj * A0;
        T1[u] += wj * A1;
        T2[u] += wj * A2;
      }
    }
  }
#pragma unroll
  for (int u = 0; u < 4; ++u) {
    if (!act[u]) continue;
    int v = vv[u];
    const u16* vp = &VP[(size_t)b*NPAD + (size_t)v*3];
    float p0 = b2f(vp[0]), p1 = b2f(vp[1]), p2 = b2f(vp[2]);
    float x = T0[u][0]*p0 + T0[u][1]*p1 + T0[u][2]*p2 + T0[u][3] + trs[0];
    float y = T1[u][0]*p0 + T1[u][1]*p1 + T1[u][2]*p2 + T1[u][3] + trs[1];
    float z = T2[u][0]*p0 + T2[u][1]*p1 + T2[u][2]*p2 + T2[u][3] + trs[2];
    size_t o = ((size_t)b*V_SZ + v)*3;
    out[o+0] = x; out[o+1] = y; out[o+2] = z;
  }
}

// ---------------------------------------------------------------------------
extern "C" void kernel_launch(void* const* d_in, const int* in_sizes, int n_in,
                              void* d_out, int out_size, void* d_ws, size_t ws_size,
                              hipStream_t stream) {
  const float* body_pose     = (const float*)d_in[0];
  const float* betas         = (const float*)d_in[1];
  const float* global_orient = (const float*)d_in[2];
  const float* transl        = (const float*)d_in[3];
  const float* v_template    = (const float*)d_in[4];
  const float* shapedirs     = (const float*)d_in[5];
  const float* posedirs      = (const float*)d_in[6];
  const float* J_template    = (const float*)d_in[7];
  const float* J_shapedirs   = (const float*)d_in[8];
  const float* lbsw          = (const float*)d_in[9];
  float* out = (float*)d_out;

  // workspace layout (needs ~64.5 MB)
  char* ws = (char*)d_ws;
  u16*   PF  = (u16*)(ws + 0);                    // 1024*480*2      = 0.94 MB
  float* Afp = (float*)(ws + (1u << 20));         // 1024*52*12*4    = 2.44 MB
  u16*   PDt = (u16*)(ws + (4u << 20));           // 20736*480*2     = 18.98 MB
  u16*   VP  = (u16*)(ws + (24u << 20));          // 1024*20736*2    = 40.5 MB

  k0_build_pdt<<<dim3(648, 15), dim3(32, 8), 0, stream>>>(posedirs, shapedirs, PDt);
  k1_prep<<<dim3(1024), dim3(64), 0, stream>>>(body_pose, betas, global_orient,
                                               J_template, J_shapedirs, Afp, PF);
  k2_gemm<<<dim3(162, 8), dim3(256), 0, stream>>>(PF, PDt, v_template, VP);
  k3_blend<<<dim3(7, 1024), dim3(256), 0, stream>>>(Afp, transl, lbsw, VP, out);
}

// Round 5
// 362.762 us; speedup vs baseline: 1.5493x; 1.5493x over previous
//
#include <hip/hip_runtime.h>

typedef unsigned short u16;
typedef __bf16  bf16x8 __attribute__((ext_vector_type(8)));
typedef float   f32x4  __attribute__((ext_vector_type(4)));

#define B_SZ   1024
#define V_SZ   6890
#define VPAD   6912    /* 108*64 = 27*256 */
#define J_SZ   52
#define NB_SZ  16
#define NPOSE  459
#define N3     20670   /* V*3 */
#define NPAD   20736   /* 162*128, padded N for GEMM */
#define KG     480     /* 459 pose + 16 betas, zero-padded to 480 */

__constant__ int PARENTS_D[52] = {-1,0,0,0,1,2,3,4,5,6,7,8,9,9,9,12,13,14,16,17,18,19,20,22,23,
                                  20,25,26,20,28,29,20,31,32,20,34,35,21,37,38,21,40,41,21,43,44,
                                  21,46,47,21,49,50};

__device__ __forceinline__ u16 f2b(float f) {
  union { float f; unsigned u; } v; v.f = f;
  unsigned r = (v.u + 0x7FFFu + ((v.u >> 16) & 1u)) >> 16;
  return (u16)r;
}
__device__ __forceinline__ float b2f(u16 h) {
  union { unsigned u; float f; } v; v.u = ((unsigned)h) << 16;
  return v.f;
}
__device__ __forceinline__ void async16(const void* g, void* l) {
  __builtin_amdgcn_global_load_lds((const __attribute__((address_space(1))) void*)g,
                                   (__attribute__((address_space(3))) void*)l, 16, 0, 0);
}

// ---------------------------------------------------------------------------
// K0: build PDt[n][k] (bf16, K-contiguous). (r1-verified, unchanged)
// ---------------------------------------------------------------------------
__global__ __launch_bounds__(256) void k0_build_pdt(const float* __restrict__ posedirs,
                                                    const float* __restrict__ shapedirs,
                                                    u16* __restrict__ PDt)
{
  __shared__ u16 tile[32][33];
  const int tx = threadIdx.x;          // 32
  const int ty = threadIdx.y;          // 8
  const int n0 = blockIdx.x * 32;
  const int k0 = blockIdx.y * 32;
#pragma unroll
  for (int i = 0; i < 4; ++i) {
    int k = k0 + ty + i*8;
    int n = n0 + tx;
    float val = 0.f;
    if (n < N3) {
      if (k < NPOSE)              val = posedirs[(size_t)k * N3 + n];
      else if (k < NPOSE + NB_SZ) val = shapedirs[(size_t)n * NB_SZ + (k - NPOSE)];
    }
    tile[ty + i*8][tx] = f2b(val);
  }
  __syncthreads();
#pragma unroll
  for (int i = 0; i < 4; ++i) {
    int n = n0 + ty + i*8;
    int k = k0 + tx;
    PDt[(size_t)n * KG + k] = tile[tx][ty + i*8];
  }
}

// ---------------------------------------------------------------------------
// K0c: WT[j][v] = lbsw[v][j] fp32 transpose (v>=V_SZ -> 0). Coalesced load
// (flat row-major) -> LDS stride-53 tile -> coalesced store per j-row.
// Runs after k2; WT lives in the then-dead PDt region.
// ---------------------------------------------------------------------------
__global__ __launch_bounds__(256) void k0c_wt(const float* __restrict__ lbsw,
                                              float* __restrict__ WT)
{
  __shared__ float tile[256 * 53];
  const int tid = threadIdx.x;
  const int v0  = blockIdx.x * 256;
  for (int f = tid; f < 256 * J_SZ; f += 256) {
    int vl = f / J_SZ;
    int j  = f - vl * J_SZ;
    float val = ((size_t)v0 * J_SZ + f < (size_t)V_SZ * J_SZ)
                ? lbsw[(size_t)v0 * J_SZ + f] : 0.f;
    tile[vl * 53 + j] = val;
  }
  __syncthreads();
  for (int j = 0; j < J_SZ; ++j)
    WT[(size_t)j * VPAD + v0 + tid] = tile[tid * 53 + j];   // lanes consecutive
}

// ---------------------------------------------------------------------------
// K1: per batch: rot6d -> R, joints, kinematic chain -> A (3x4 fp32),
// pose_feature||betas -> PF bf16 row. (r1-verified version, Afp fp32 output)
// ---------------------------------------------------------------------------
__global__ __launch_bounds__(64) void k1_prep(const float* __restrict__ body_pose,
                                              const float* __restrict__ betas,
                                              const float* __restrict__ global_orient,
                                              const float* __restrict__ J_template,
                                              const float* __restrict__ J_shapedirs,
                                              float* __restrict__ Afp,
                                              u16* __restrict__ PF)
{
  __shared__ float R[J_SZ][9];
  __shared__ float jts[J_SZ][3];
  __shared__ float G[J_SZ][12];
  const int b   = blockIdx.x;
  const int tid = threadIdx.x;

  if (tid < J_SZ) {
    const float* d6 = (tid == 0) ? &global_orient[(size_t)b * 6]
                                 : &body_pose[((size_t)b * 51 + (tid - 1)) * 6];
    float a1x = d6[0], a1y = d6[1], a1z = d6[2];
    float a2x = d6[3], a2y = d6[4], a2z = d6[5];
    float inv1 = rsqrtf(a1x*a1x + a1y*a1y + a1z*a1z);
    float b1x = a1x*inv1, b1y = a1y*inv1, b1z = a1z*inv1;
    float d   = b1x*a2x + b1y*a2y + b1z*a2z;
    float ux = a2x - d*b1x, uy = a2y - d*b1y, uz = a2z - d*b1z;
    float inv2 = rsqrtf(ux*ux + uy*uy + uz*uz);
    float b2x = ux*inv2, b2y = uy*inv2, b2z = uz*inv2;
    float b3x = b1y*b2z - b1z*b2y;
    float b3y = b1z*b2x - b1x*b2z;
    float b3z = b1x*b2y - b1y*b2x;
    R[tid][0]=b1x; R[tid][1]=b1y; R[tid][2]=b1z;
    R[tid][3]=b2x; R[tid][4]=b2y; R[tid][5]=b2z;
    R[tid][6]=b3x; R[tid][7]=b3y; R[tid][8]=b3z;
#pragma unroll
    for (int c = 0; c < 3; ++c) {
      float s = J_template[tid*3 + c];
#pragma unroll
      for (int k = 0; k < NB_SZ; ++k)
        s += betas[(size_t)b*NB_SZ + k] * J_shapedirs[(tid*3 + c)*NB_SZ + k];
      jts[tid][c] = s;
    }
  }
  __syncthreads();

  if (tid == 0) {   // serial kinematic chain
#pragma unroll
    for (int c = 0; c < 3; ++c) {
      G[0][c*4+0] = R[0][c*3+0];
      G[0][c*4+1] = R[0][c*3+1];
      G[0][c*4+2] = R[0][c*3+2];
      G[0][c*4+3] = jts[0][c];
    }
    for (int j = 1; j < J_SZ; ++j) {
      int p = PARENTS_D[j];
      float r0 = jts[j][0] - jts[p][0];
      float r1 = jts[j][1] - jts[p][1];
      float r2 = jts[j][2] - jts[p][2];
      for (int c = 0; c < 3; ++c) {
        float g0 = G[p][c*4+0], g1 = G[p][c*4+1], g2 = G[p][c*4+2];
        G[j][c*4+0] = g0*R[j][0] + g1*R[j][3] + g2*R[j][6];
        G[j][c*4+1] = g0*R[j][1] + g1*R[j][4] + g2*R[j][7];
        G[j][c*4+2] = g0*R[j][2] + g1*R[j][5] + g2*R[j][8];
        G[j][c*4+3] = g0*r0 + g1*r1 + g2*r2 + G[p][c*4+3];
      }
    }
  }
  __syncthreads();

  if (tid < J_SZ) {  // t_corr + write A (fp32, [b][j][12])
    float o[12];
#pragma unroll
    for (int i = 0; i < 12; ++i) o[i] = G[tid][i];
#pragma unroll
    for (int c = 0; c < 3; ++c)
      o[c*4+3] -= o[c*4+0]*jts[tid][0] + o[c*4+1]*jts[tid][1] + o[c*4+2]*jts[tid][2];
#pragma unroll
    for (int i = 0; i < 12; ++i) Afp[((size_t)b*J_SZ + tid)*12 + i] = o[i];
  }

  for (int k = tid; k < KG; k += 64) {  // PF row: pose_feature | betas | 0-pad
    float val = 0.f;
    if (k < NPOSE) {
      int j  = k / 9 + 1;
      int rc = k - (j - 1) * 9;
      val = R[j][rc] - ((rc == 0 || rc == 4 || rc == 8) ? 1.f : 0.f);
    } else if (k < NPOSE + NB_SZ) {
      val = betas[(size_t)b*NB_SZ + (k - NPOSE)];
    }
    PF[(size_t)b*KG + k] = f2b(val);
  }
}

// ---------------------------------------------------------------------------
// K2: v_posed(B, NPAD) = PF(B,KG) @ PDt^T + v_template bias, bf16 MFMA.
// (r1-verified, unchanged)
// ---------------------------------------------------------------------------
__global__ __launch_bounds__(256) void k2_gemm(const u16* __restrict__ PF,
                                               const u16* __restrict__ PDt,
                                               const float* __restrict__ vtmpl,
                                               u16* __restrict__ VP)
{
  __shared__ __align__(16) u16 lA[128*32];
  __shared__ __align__(16) u16 lB[128*32];
  const int tid  = threadIdx.x;
  const int lane = tid & 63;
  const int w    = tid >> 6;
  const int n0   = blockIdx.x * 128;
  const int b0   = blockIdx.y * 128;
  const int moff = (w & 1) * 64;
  const int noff = (w >> 1) * 64;
  const int q    = lane >> 4;
  const int lrow = lane & 15;

  f32x4 acc[4][4];
#pragma unroll
  for (int i = 0; i < 4; ++i)
#pragma unroll
    for (int j = 0; j < 4; ++j) { f32x4 z = {0.f,0.f,0.f,0.f}; acc[i][j] = z; }

  int aoff[4], boff[4];
#pragma unroll
  for (int i = 0; i < 4; ++i) {
    int ra = moff + i*16 + lrow;
    aoff[i] = ra*32 + (q ^ ((ra + (ra >> 2)) & 3)) * 8;
    int rb = noff + i*16 + lrow;
    boff[i] = rb*32 + (q ^ ((rb + (rb >> 2)) & 3)) * 8;
  }
  int srow[2], schunk[2];
#pragma unroll
  for (int t = 0; t < 2; ++t) {
    int i = (t*4 + w)*64 + lane;     // slot in [0,512)
    int r = i >> 2;
    srow[t]   = r;
    schunk[t] = (i & 3) ^ ((r + (r >> 2)) & 3);
  }

  for (int k0 = 0; k0 < KG; k0 += 32) {
#pragma unroll
    for (int t = 0; t < 2; ++t) {
      async16(PF  + (size_t)(b0 + srow[t])*KG + k0 + schunk[t]*8, &lA[(t*4 + w)*512]);
      async16(PDt + (size_t)(n0 + srow[t])*KG + k0 + schunk[t]*8, &lB[(t*4 + w)*512]);
    }
    __syncthreads();
    bf16x8 af[4], bfv[4];
#pragma unroll
    for (int i = 0; i < 4; ++i) af[i]  = *(const bf16x8*)&lA[aoff[i]];
#pragma unroll
    for (int i = 0; i < 4; ++i) bfv[i] = *(const bf16x8*)&lB[boff[i]];
#pragma unroll
    for (int i = 0; i < 4; ++i)
#pragma unroll
      for (int j = 0; j < 4; ++j)
        acc[i][j] = __builtin_amdgcn_mfma_f32_16x16x32_bf16(af[i], bfv[j], acc[i][j], 0, 0, 0);
    __syncthreads();
  }

#pragma unroll
  for (int i = 0; i < 4; ++i) {
    int brow = b0 + moff + i*16 + q*4;
#pragma unroll
    for (int j = 0; j < 4; ++j) {
      int n = n0 + noff + j*16 + lrow;
      if (n < N3) {
        float bias = vtmpl[n];
#pragma unroll
        for (int r = 0; r < 4; ++r)
          VP[(size_t)(brow + r)*NPAD + n] = f2b(acc[i][j][r] + bias);
      }
    }
  }
}

// ---------------------------------------------------------------------------
// K3: r1-verified scalar blend, with the ONE change that fixes its 400 us:
// weights come from the transposed WT[j][v] so lanes read consecutive
// addresses (1 transaction/wave instead of ~52). All else identical to r1.
// ---------------------------------------------------------------------------
__global__ __launch_bounds__(256) void k3_blend(const float* __restrict__ Afp,
                                                const float* __restrict__ transl,
                                                const float* __restrict__ WT,
                                                const u16* __restrict__ VP,
                                                float* __restrict__ out)
{
  __shared__ float As[J_SZ*12];
  __shared__ float trs[3];
  const int tid = threadIdx.x;
  const int b   = blockIdx.y;
  for (int i = tid; i < J_SZ*12; i += 256) As[i] = Afp[(size_t)b*(J_SZ*12) + i];
  if (tid < 3) trs[tid] = transl[b*3 + tid];
  __syncthreads();

  int vv[4]; bool act[4];
#pragma unroll
  for (int u = 0; u < 4; ++u) {
    vv[u]  = blockIdx.x*1024 + u*256 + tid;
    act[u] = vv[u] < V_SZ;
  }
  f32x4 T0[4], T1[4], T2[4];
#pragma unroll
  for (int u = 0; u < 4; ++u) { f32x4 z = {0.f,0.f,0.f,0.f}; T0[u]=z; T1[u]=z; T2[u]=z; }

  for (int j = 0; j < J_SZ; ++j) {
    f32x4 A0 = *(const f32x4*)&As[j*12 + 0];
    f32x4 A1 = *(const f32x4*)&As[j*12 + 4];
    f32x4 A2 = *(const f32x4*)&As[j*12 + 8];
    float wj[4];
#pragma unroll
    for (int u = 0; u < 4; ++u)
      wj[u] = act[u] ? WT[(size_t)j*VPAD + vv[u]] : 0.f;
#pragma unroll
    for (int u = 0; u < 4; ++u) {
      T0[u] += wj[u] * A0;
      T1[u] += wj[u] * A1;
      T2[u] += wj[u] * A2;
    }
  }
#pragma unroll
  for (int u = 0; u < 4; ++u) {
    if (!act[u]) continue;
    int v = vv[u];
    const u16* vp = &VP[(size_t)b*NPAD + (size_t)v*3];
    float p0 = b2f(vp[0]), p1 = b2f(vp[1]), p2 = b2f(vp[2]);
    float x = T0[u][0]*p0 + T0[u][1]*p1 + T0[u][2]*p2 + T0[u][3] + trs[0];
    float y = T1[u][0]*p0 + T1[u][1]*p1 + T1[u][2]*p2 + T1[u][3] + trs[1];
    float z = T2[u][0]*p0 + T2[u][1]*p1 + T2[u][2]*p2 + T2[u][3] + trs[2];
    size_t o = ((size_t)b*V_SZ + v)*3;
    out[o+0] = x; out[o+1] = y; out[o+2] = z;
  }
}

// ---------------------------------------------------------------------------
extern "C" void kernel_launch(void* const* d_in, const int* in_sizes, int n_in,
                              void* d_out, int out_size, void* d_ws, size_t ws_size,
                              hipStream_t stream) {
  const float* body_pose     = (const float*)d_in[0];
  const float* betas         = (const float*)d_in[1];
  const float* global_orient = (const float*)d_in[2];
  const float* transl        = (const float*)d_in[3];
  const float* v_template    = (const float*)d_in[4];
  const float* shapedirs     = (const float*)d_in[5];
  const float* posedirs      = (const float*)d_in[6];
  const float* J_template    = (const float*)d_in[7];
  const float* J_shapedirs   = (const float*)d_in[8];
  const float* lbsw          = (const float*)d_in[9];
  float* out = (float*)d_out;

  // workspace layout (64.5 MB):
  //   [0, 1 MB)    PF  (k1->k2)               1024*480*2 = 0.94 MB
  //   [1, 4 MB)    Afp (k1->k3)               1024*52*12*4 = 2.44 MB
  //   [5, 24 MB)   PDt (k0->k2); dead after k2, first 1.5 MB reused as
  //                  WT fp32 [52][VPAD] (k0c->k3) = 1.44 MB
  //   [24, 64.5)   VP  (k2->k3)               1024*NPAD*2 = 40.5 MB
  char* ws = (char*)d_ws;
  u16*   PF  = (u16*)(ws + 0);
  float* Afp = (float*)(ws + (1u << 20));
  u16*   PDt = (u16*)(ws + (5u << 20));
  float* WT  = (float*)(ws + (5u << 20));   // overlays PDt (dead after k2)
  u16*   VP  = (u16*)(ws + (24u << 20));

  k0_build_pdt<<<dim3(648, 15), dim3(32, 8), 0, stream>>>(posedirs, shapedirs, PDt);
  k1_prep<<<dim3(1024), dim3(64), 0, stream>>>(body_pose, betas, global_orient,
                                               J_template, J_shapedirs, Afp, PF);
  k2_gemm<<<dim3(162, 8), dim3(256), 0, stream>>>(PF, PDt, v_template, VP);
  k0c_wt<<<dim3(VPAD / 256), dim3(256), 0, stream>>>(lbsw, WT);
  k3_blend<<<dim3(7, 1024), dim3(256), 0, stream>>>(Afp, transl, WT, VP, out);
}

// Round 6
// 339.966 us; speedup vs baseline: 1.6532x; 1.0671x over previous
//
#include <hip/hip_runtime.h>

typedef unsigned short u16;
typedef __bf16  bf16x8 __attribute__((ext_vector_type(8)));
typedef float   f32x4  __attribute__((ext_vector_type(4)));
typedef float   f32x2  __attribute__((ext_vector_type(2)));

#define B_SZ   1024
#define V_SZ   6890
#define VPAD2  7168    /* 28*256, WT column pad (7 blocks * 1024 verts) */
#define J_SZ   52
#define NB_SZ  16
#define NPOSE  459
#define N3     20670   /* V*3 */
#define NPAD   20736   /* 162*128, padded N for GEMM */
#define KG     480     /* 459 pose + 16 betas, zero-padded to 480 */

__constant__ int PARENTS_D[52] = {-1,0,0,0,1,2,3,4,5,6,7,8,9,9,9,12,13,14,16,17,18,19,20,22,23,
                                  20,25,26,20,28,29,20,31,32,20,34,35,21,37,38,21,40,41,21,43,44,
                                  21,46,47,21,49,50};

__device__ __forceinline__ u16 f2b(float f) {
  union { float f; unsigned u; } v; v.f = f;
  unsigned r = (v.u + 0x7FFFu + ((v.u >> 16) & 1u)) >> 16;
  return (u16)r;
}
__device__ __forceinline__ float b2f(u16 h) {
  union { unsigned u; float f; } v; v.u = ((unsigned)h) << 16;
  return v.f;
}
__device__ __forceinline__ void async16(const void* g, void* l) {
  __builtin_amdgcn_global_load_lds((const __attribute__((address_space(1))) void*)g,
                                   (__attribute__((address_space(3))) void*)l, 16, 0, 0);
}

// ---------------------------------------------------------------------------
// K0: build PDt[n][k] (bf16, K-contiguous). (r1-verified, unchanged)
// ---------------------------------------------------------------------------
__global__ __launch_bounds__(256) void k0_build_pdt(const float* __restrict__ posedirs,
                                                    const float* __restrict__ shapedirs,
                                                    u16* __restrict__ PDt)
{
  __shared__ u16 tile[32][33];
  const int tx = threadIdx.x;          // 32
  const int ty = threadIdx.y;          // 8
  const int n0 = blockIdx.x * 32;
  const int k0 = blockIdx.y * 32;
#pragma unroll
  for (int i = 0; i < 4; ++i) {
    int k = k0 + ty + i*8;
    int n = n0 + tx;
    float val = 0.f;
    if (n < N3) {
      if (k < NPOSE)              val = posedirs[(size_t)k * N3 + n];
      else if (k < NPOSE + NB_SZ) val = shapedirs[(size_t)n * NB_SZ + (k - NPOSE)];
    }
    tile[ty + i*8][tx] = f2b(val);
  }
  __syncthreads();
#pragma unroll
  for (int i = 0; i < 4; ++i) {
    int n = n0 + ty + i*8;
    int k = k0 + tx;
    PDt[(size_t)n * KG + k] = tile[tx][ty + i*8];
  }
}

// ---------------------------------------------------------------------------
// K0c: WT[j][v] = lbsw[v][j] fp32 transpose, v padded to VPAD2 with zeros.
// Coalesced flat load -> LDS stride-53 tile -> coalesced store per j-row.
// (r5-verified pattern, columns now padded to 7168)
// ---------------------------------------------------------------------------
__global__ __launch_bounds__(256) void k0c_wt(const float* __restrict__ lbsw,
                                              float* __restrict__ WT)
{
  __shared__ float tile[256 * 53];
  const int tid = threadIdx.x;
  const int v0  = blockIdx.x * 256;
  for (int f = tid; f < 256 * J_SZ; f += 256) {
    int vl = f / J_SZ;
    int j  = f - vl * J_SZ;
    float val = ((size_t)v0 * J_SZ + f < (size_t)V_SZ * J_SZ)
                ? lbsw[(size_t)v0 * J_SZ + f] : 0.f;
    tile[vl * 53 + j] = val;
  }
  __syncthreads();
  for (int j = 0; j < J_SZ; ++j)
    WT[(size_t)j * VPAD2 + v0 + tid] = tile[tid * 53 + j];   // lanes consecutive
}

// ---------------------------------------------------------------------------
// K1: per batch: rot6d -> R, joints, chain -> A (fp32 [b][j][12]), PF bf16.
// (r1/r5-verified, unchanged)
// ---------------------------------------------------------------------------
__global__ __launch_bounds__(64) void k1_prep(const float* __restrict__ body_pose,
                                              const float* __restrict__ betas,
                                              const float* __restrict__ global_orient,
                                              const float* __restrict__ J_template,
                                              const float* __restrict__ J_shapedirs,
                                              float* __restrict__ Afp,
                                              u16* __restrict__ PF)
{
  __shared__ float R[J_SZ][9];
  __shared__ float jts[J_SZ][3];
  __shared__ float G[J_SZ][12];
  const int b   = blockIdx.x;
  const int tid = threadIdx.x;

  if (tid < J_SZ) {
    const float* d6 = (tid == 0) ? &global_orient[(size_t)b * 6]
                                 : &body_pose[((size_t)b * 51 + (tid - 1)) * 6];
    float a1x = d6[0], a1y = d6[1], a1z = d6[2];
    float a2x = d6[3], a2y = d6[4], a2z = d6[5];
    float inv1 = rsqrtf(a1x*a1x + a1y*a1y + a1z*a1z);
    float b1x = a1x*inv1, b1y = a1y*inv1, b1z = a1z*inv1;
    float d   = b1x*a2x + b1y*a2y + b1z*a2z;
    float ux = a2x - d*b1x, uy = a2y - d*b1y, uz = a2z - d*b1z;
    float inv2 = rsqrtf(ux*ux + uy*uy + uz*uz);
    float b2x = ux*inv2, b2y = uy*inv2, b2z = uz*inv2;
    float b3x = b1y*b2z - b1z*b2y;
    float b3y = b1z*b2x - b1x*b2z;
    float b3z = b1x*b2y - b1y*b2x;
    R[tid][0]=b1x; R[tid][1]=b1y; R[tid][2]=b1z;
    R[tid][3]=b2x; R[tid][4]=b2y; R[tid][5]=b2z;
    R[tid][6]=b3x; R[tid][7]=b3y; R[tid][8]=b3z;
#pragma unroll
    for (int c = 0; c < 3; ++c) {
      float s = J_template[tid*3 + c];
#pragma unroll
      for (int k = 0; k < NB_SZ; ++k)
        s += betas[(size_t)b*NB_SZ + k] * J_shapedirs[(tid*3 + c)*NB_SZ + k];
      jts[tid][c] = s;
    }
  }
  __syncthreads();

  if (tid == 0) {   // serial kinematic chain
#pragma unroll
    for (int c = 0; c < 3; ++c) {
      G[0][c*4+0] = R[0][c*3+0];
      G[0][c*4+1] = R[0][c*3+1];
      G[0][c*4+2] = R[0][c*3+2];
      G[0][c*4+3] = jts[0][c];
    }
    for (int j = 1; j < J_SZ; ++j) {
      int p = PARENTS_D[j];
      float r0 = jts[j][0] - jts[p][0];
      float r1 = jts[j][1] - jts[p][1];
      float r2 = jts[j][2] - jts[p][2];
      for (int c = 0; c < 3; ++c) {
        float g0 = G[p][c*4+0], g1 = G[p][c*4+1], g2 = G[p][c*4+2];
        G[j][c*4+0] = g0*R[j][0] + g1*R[j][3] + g2*R[j][6];
        G[j][c*4+1] = g0*R[j][1] + g1*R[j][4] + g2*R[j][7];
        G[j][c*4+2] = g0*R[j][2] + g1*R[j][5] + g2*R[j][8];
        G[j][c*4+3] = g0*r0 + g1*r1 + g2*r2 + G[p][c*4+3];
      }
    }
  }
  __syncthreads();

  if (tid < J_SZ) {  // t_corr + write A (fp32, [b][j][12])
    float o[12];
#pragma unroll
    for (int i = 0; i < 12; ++i) o[i] = G[tid][i];
#pragma unroll
    for (int c = 0; c < 3; ++c)
      o[c*4+3] -= o[c*4+0]*jts[tid][0] + o[c*4+1]*jts[tid][1] + o[c*4+2]*jts[tid][2];
#pragma unroll
    for (int i = 0; i < 12; ++i) Afp[((size_t)b*J_SZ + tid)*12 + i] = o[i];
  }

  for (int k = tid; k < KG; k += 64) {  // PF row: pose_feature | betas | 0-pad
    float val = 0.f;
    if (k < NPOSE) {
      int j  = k / 9 + 1;
      int rc = k - (j - 1) * 9;
      val = R[j][rc] - ((rc == 0 || rc == 4 || rc == 8) ? 1.f : 0.f);
    } else if (k < NPOSE + NB_SZ) {
      val = betas[(size_t)b*NB_SZ + (k - NPOSE)];
    }
    PF[(size_t)b*KG + k] = f2b(val);
  }
}

// ---------------------------------------------------------------------------
// K2: v_posed(B, NPAD) = PF(B,KG) @ PDt^T + v_template bias, bf16 MFMA.
// (r1-verified, unchanged)
// ---------------------------------------------------------------------------
__global__ __launch_bounds__(256) void k2_gemm(const u16* __restrict__ PF,
                                               const u16* __restrict__ PDt,
                                               const float* __restrict__ vtmpl,
                                               u16* __restrict__ VP)
{
  __shared__ __align__(16) u16 lA[128*32];
  __shared__ __align__(16) u16 lB[128*32];
  const int tid  = threadIdx.x;
  const int lane = tid & 63;
  const int w    = tid >> 6;
  const int n0   = blockIdx.x * 128;
  const int b0   = blockIdx.y * 128;
  const int moff = (w & 1) * 64;
  const int noff = (w >> 1) * 64;
  const int q    = lane >> 4;
  const int lrow = lane & 15;

  f32x4 acc[4][4];
#pragma unroll
  for (int i = 0; i < 4; ++i)
#pragma unroll
    for (int j = 0; j < 4; ++j) { f32x4 z = {0.f,0.f,0.f,0.f}; acc[i][j] = z; }

  int aoff[4], boff[4];
#pragma unroll
  for (int i = 0; i < 4; ++i) {
    int ra = moff + i*16 + lrow;
    aoff[i] = ra*32 + (q ^ ((ra + (ra >> 2)) & 3)) * 8;
    int rb = noff + i*16 + lrow;
    boff[i] = rb*32 + (q ^ ((rb + (rb >> 2)) & 3)) * 8;
  }
  int srow[2], schunk[2];
#pragma unroll
  for (int t = 0; t < 2; ++t) {
    int i = (t*4 + w)*64 + lane;     // slot in [0,512)
    int r = i >> 2;
    srow[t]   = r;
    schunk[t] = (i & 3) ^ ((r + (r >> 2)) & 3);
  }

  for (int k0 = 0; k0 < KG; k0 += 32) {
#pragma unroll
    for (int t = 0; t < 2; ++t) {
      async16(PF  + (size_t)(b0 + srow[t])*KG + k0 + schunk[t]*8, &lA[(t*4 + w)*512]);
      async16(PDt + (size_t)(n0 + srow[t])*KG + k0 + schunk[t]*8, &lB[(t*4 + w)*512]);
    }
    __syncthreads();
    bf16x8 af[4], bfv[4];
#pragma unroll
    for (int i = 0; i < 4; ++i) af[i]  = *(const bf16x8*)&lA[aoff[i]];
#pragma unroll
    for (int i = 0; i < 4; ++i) bfv[i] = *(const bf16x8*)&lB[boff[i]];
#pragma unroll
    for (int i = 0; i < 4; ++i)
#pragma unroll
      for (int j = 0; j < 4; ++j)
        acc[i][j] = __builtin_amdgcn_mfma_f32_16x16x32_bf16(af[i], bfv[j], acc[i][j], 0, 0, 0);
    __syncthreads();
  }

#pragma unroll
  for (int i = 0; i < 4; ++i) {
    int brow = b0 + moff + i*16 + q*4;
#pragma unroll
    for (int j = 0; j < 4; ++j) {
      int n = n0 + noff + j*16 + lrow;
      if (n < N3) {
        float bias = vtmpl[n];
#pragma unroll
        for (int r = 0; r < 4; ++r)
          VP[(size_t)(brow + r)*NPAD + n] = f2b(acc[i][j][r] + bias);
      }
    }
  }
}

// ---------------------------------------------------------------------------
// K3: scalar blend (r5-verified math), verts now CONSECUTIVE per thread:
// one float4 WT load per j (guard-free, WT zero-padded to VPAD2), 48 FMAs,
// 3 wave-uniform LDS reads. Epilogue: contiguous VP reads, float2 out stores.
// ---------------------------------------------------------------------------
__global__ __launch_bounds__(256) void k3_blend(const float* __restrict__ Afp,
                                                const float* __restrict__ transl,
                                                const float* __restrict__ WT,
                                                const u16* __restrict__ VP,
                                                float* __restrict__ out)
{
  __shared__ float As[J_SZ*12];
  __shared__ float trs[3];
  const int tid = threadIdx.x;
  const int b   = blockIdx.y;
  for (int i = tid; i < J_SZ*12; i += 256) As[i] = Afp[(size_t)b*(J_SZ*12) + i];
  if (tid < 3) trs[tid] = transl[b*3 + tid];
  __syncthreads();

  const int base = blockIdx.x * 1024 + tid * 4;   // 4 consecutive verts

  f32x4 T0[4], T1[4], T2[4];
#pragma unroll
  for (int u = 0; u < 4; ++u) { f32x4 z = {0.f,0.f,0.f,0.f}; T0[u]=z; T1[u]=z; T2[u]=z; }

  for (int j = 0; j < J_SZ; ++j) {
    f32x4 wv = *(const f32x4*)&WT[(size_t)j*VPAD2 + base];  // 16B, coalesced
    f32x4 A0 = *(const f32x4*)&As[j*12 + 0];
    f32x4 A1 = *(const f32x4*)&As[j*12 + 4];
    f32x4 A2 = *(const f32x4*)&As[j*12 + 8];
#pragma unroll
    for (int u = 0; u < 4; ++u) {
      T0[u] += wv[u] * A0;
      T1[u] += wv[u] * A1;
      T2[u] += wv[u] * A2;
    }
  }

  if (base + 3 < V_SZ) {           // fast path: 4 full verts
    // VP: 12 consecutive u16 (24 B, 8-aligned) -> 3x 8B loads
    const u16* vp = &VP[(size_t)b*NPAD + (size_t)base*3];
    u16 pv[12];
#pragma unroll
    for (int c = 0; c < 3; ++c)
      *(uint2*)&pv[c*4] = *(const uint2*)&vp[c*4];
    float vals[12];
#pragma unroll
    for (int u = 0; u < 4; ++u) {
      float p0 = b2f(pv[u*3+0]), p1 = b2f(pv[u*3+1]), p2 = b2f(pv[u*3+2]);
      vals[u*3+0] = T0[u][0]*p0 + T0[u][1]*p1 + T0[u][2]*p2 + T0[u][3] + trs[0];
      vals[u*3+1] = T1[u][0]*p0 + T1[u][1]*p1 + T1[u][2]*p2 + T1[u][3] + trs[1];
      vals[u*3+2] = T2[u][0]*p0 + T2[u][1]*p1 + T2[u][2]*p2 + T2[u][3] + trs[2];
    }
    float* op = &out[((size_t)b*V_SZ + base)*3];   // 48 B, 8-aligned
#pragma unroll
    for (int c = 0; c < 6; ++c)
      *(f32x2*)&op[c*2] = *(const f32x2*)&vals[c*2];
  } else if (base < V_SZ) {        // tail: per-vert scalar
#pragma unroll
    for (int u = 0; u < 4; ++u) {
      int v = base + u;
      if (v >= V_SZ) continue;
      const u16* vp = &VP[(size_t)b*NPAD + (size_t)v*3];
      float p0 = b2f(vp[0]), p1 = b2f(vp[1]), p2 = b2f(vp[2]);
      size_t o = ((size_t)b*V_SZ + v)*3;
      out[o+0] = T0[u][0]*p0 + T0[u][1]*p1 + T0[u][2]*p2 + T0[u][3] + trs[0];
      out[o+1] = T1[u][0]*p0 + T1[u][1]*p1 + T1[u][2]*p2 + T1[u][3] + trs[1];
      out[o+2] = T2[u][0]*p0 + T2[u][1]*p1 + T2[u][2]*p2 + T2[u][3] + trs[2];
    }
  }
}

// ---------------------------------------------------------------------------
extern "C" void kernel_launch(void* const* d_in, const int* in_sizes, int n_in,
                              void* d_out, int out_size, void* d_ws, size_t ws_size,
                              hipStream_t stream) {
  const float* body_pose     = (const float*)d_in[0];
  const float* betas         = (const float*)d_in[1];
  const float* global_orient = (const float*)d_in[2];
  const float* transl        = (const float*)d_in[3];
  const float* v_template    = (const float*)d_in[4];
  const float* shapedirs     = (const float*)d_in[5];
  const float* posedirs      = (const float*)d_in[6];
  const float* J_template    = (const float*)d_in[7];
  const float* J_shapedirs   = (const float*)d_in[8];
  const float* lbsw          = (const float*)d_in[9];
  float* out = (float*)d_out;

  // workspace layout (64.5 MB):
  //   [0, 0.94)    PF  (k1->k2)
  //   [1, 3.44)    Afp (k1->k3)
  //   [3.5, 4.99)  WT  fp32 [52][7168] (k0c->k3)  1.49 MB  (no PDt overlay)
  //   [5, 24)      PDt (k0->k2)
  //   [24, 64.5)   VP  (k2->k3)
  char* ws = (char*)d_ws;
  u16*   PF  = (u16*)(ws + 0);
  float* Afp = (float*)(ws + (1u << 20));
  float* WT  = (float*)(ws + 3584u * 1024u);
  u16*   PDt = (u16*)(ws + (5u << 20));
  u16*   VP  = (u16*)(ws + (24u << 20));

  k0_build_pdt<<<dim3(648, 15), dim3(32, 8), 0, stream>>>(posedirs, shapedirs, PDt);
  k0c_wt<<<dim3(VPAD2 / 256), dim3(256), 0, stream>>>(lbsw, WT);
  k1_prep<<<dim3(1024), dim3(64), 0, stream>>>(body_pose, betas, global_orient,
                                               J_template, J_shapedirs, Afp, PF);
  k2_gemm<<<dim3(162, 8), dim3(256), 0, stream>>>(PF, PDt, v_template, VP);
  k3_blend<<<dim3(7, 1024), dim3(256), 0, stream>>>(Afp, transl, WT, VP, out);
}